// Round 3
// baseline (4618.900 us; speedup 1.0000x reference)
//
#include <hip/hip_runtime.h>
#include <cstdint>

// ODEBlock: 16 RK4 steps of f(t,y) = tanh(y@W1 + b1 + t) @ W2 + b2
// B=1024 (M), D=512, H=2048. bf16 MFMA, fp32 state/epilogues.
// R2: single persistent mega-kernel, grid=256 (1 block/CU via 144KB LDS),
//     weights pinned in LDS (XOR-swizzled), DIY grid barrier, 3 phases/stage.

typedef __bf16 bf16x8 __attribute__((ext_vector_type(8)));
typedef float f32x4 __attribute__((ext_vector_type(4)));

#define AS1 __attribute__((address_space(1)))
#define AS3 __attribute__((address_space(3)))

#define MDIM 1024
#define DDIM 512
#define HDIM 2048
#define NBLK 256
#define DYN_LDS (64*1024 + 64*1024 + 16*1024)   // sW1 + sW2 + sA dbuf = 144KB

__device__ __forceinline__ void async_copy16(const void* g, void* lds) {
  __builtin_amdgcn_global_load_lds((const AS1 void*)g, (AS3 void*)lds, 16, 0, 0);
}

__device__ __forceinline__ unsigned short f32_to_bf16(float f) {
  union { float f; unsigned u; } c; c.f = f;
  unsigned u = c.u + 0x7FFFu + ((c.u >> 16) & 1u);   // RNE
  return (unsigned short)(u >> 16);
}

__device__ __forceinline__ float tanh_fast(float x) {
  float a = __builtin_fabsf(x);
  float e = __expf(-2.0f * a);
  float r = (1.0f - e) * __builtin_amdgcn_rcpf(1.0f + e);
  return __builtin_copysignf(r, x);
}

// all-block barrier: counter per use, pre-zeroed. Release: after __syncthreads
// every wave's stores are in this XCD's L2; thread0's release-add writes L2
// back. Acquire: thread0's acquire-load invalidates L1+L2 before any wave
// proceeds (trailing __syncthreads orders them).
__device__ __forceinline__ void grid_barrier(unsigned* bar, int idx) {
  __syncthreads();
  if (threadIdx.x == 0) {
    __hip_atomic_fetch_add(&bar[idx], 1u, __ATOMIC_RELEASE, __HIP_MEMORY_SCOPE_AGENT);
    while (__hip_atomic_load(&bar[idx], __ATOMIC_ACQUIRE, __HIP_MEMORY_SCOPE_AGENT) < NBLK)
      __builtin_amdgcn_s_sleep(1);
  }
  __syncthreads();
}

// ---- transpose + f32->bf16: out[c*R + r] = bf16(in[r*C + c]) --------------
__global__ __launch_bounds__(256) void transpose_bf16_kernel(
    const float* __restrict__ in, unsigned short* __restrict__ out, int R, int C) {
  __shared__ float tile[64][65];
  int nbc = C >> 6;
  int br = blockIdx.x / nbc, bc = blockIdx.x % nbc;
  int r0 = br * 64, c0 = bc * 64;
  int tr = threadIdx.x >> 6, tc = threadIdx.x & 63;
  for (int i = 0; i < 16; ++i) {
    int row = i * 4 + tr;
    tile[row][tc] = in[(r0 + row) * C + c0 + tc];
  }
  __syncthreads();
  for (int i = 0; i < 16; ++i) {
    int row = i * 4 + tr;
    out[(c0 + row) * R + r0 + tc] = f32_to_bf16(tile[tc][row]);
  }
}

// ---- init: y = x, arg = bf16(x), zero barriers ----------------------------
__global__ __launch_bounds__(256) void init_kernel(
    const float* __restrict__ x, float* __restrict__ y,
    unsigned short* __restrict__ arg, unsigned* __restrict__ bar) {
  int i = blockIdx.x * 256 + threadIdx.x;
  float v = x[i];
  y[i] = v;
  arg[i] = f32_to_bf16(v);
  if (blockIdx.x == 0) bar[threadIdx.x] = 0u;
}

// ---- persistent mega-kernel ----------------------------------------------
__global__ __launch_bounds__(256, 1) void ode_mega(
    const unsigned short* __restrict__ W1T,   // [2048,512] bf16 (K-contig)
    const unsigned short* __restrict__ W2T,   // [512,2048] bf16 (K-contig)
    const float* __restrict__ b1, const float* __restrict__ b2,
    float* __restrict__ y, float* __restrict__ kacc,
    unsigned short* __restrict__ arg,         // [1024,512] bf16
    unsigned short* __restrict__ Hbuf,        // [1024,2048] bf16
    float* __restrict__ part,                 // [4][1024,512] f32
    unsigned* __restrict__ bar)
{
  extern __shared__ char lds[];
  bf16x8* sW1 = (bf16x8*)lds;                  // 4096 units (64KB) pinned
  bf16x8* sW2 = (bf16x8*)(lds + 65536);        // 4096 units (64KB) pinned
  bf16x8* sA  = (bf16x8*)(lds + 131072);       // 2 x 512 units (16KB) staging

  const int b = blockIdx.x;
  const int tid = threadIdx.x;
  const int lane = tid & 63;
  const int wid = tid >> 6;
  const int l15 = lane & 15;
  const int l4 = lane >> 4;
  const int wm = (wid >> 1) * 64;    // wave rows (m-tiles 4x16)
  const int wn = (wid & 1) * 32;     // wave cols (n-tiles 2x16)

  // roles
  const int cg1 = b & 31;            // gemm1: 64-col group of H (x32)
  const int ms1 = b >> 5;            // gemm1: 128-row split    (x8)
  const int cg2 = b & 7;             // gemm2: 64-col group of D (x8)
  const int kc2 = (b >> 3) & 3;      // gemm2: 512-K chunk of H  (x4)
  const int ms2 = b >> 5;            // gemm2: 128-row split     (x8)

  // ---- pin weights in LDS, XOR-swizzled: unit = c*64 + (kg ^ (c&7)) ------
  {
    const float4* s1 = (const float4*)(W1T + (size_t)cg1 * 64 * DDIM); // contiguous 4096 units
    float4* d1 = (float4*)sW1;
    float4* d2 = (float4*)sW2;
    for (int u = 0; u < 16; ++u) {
      int ul = u * 256 + tid;
      int c = ul >> 6, kg = ul & 63;
      d1[c * 64 + (kg ^ (c & 7))] = s1[ul];
      const float4* s2 = (const float4*)(W2T + (size_t)(cg2 * 64 + c) * HDIM + kc2 * 512);
      d2[c * 64 + (kg ^ (c & 7))] = s2[kg];
    }
  }
  __syncthreads();

  // staging thread->element map (tile 128 rows x 32 K, unit = row*4 + kg)
  const int u0 = tid, u1 = 256 + tid;
  const int r0s = u0 >> 2, k0s = (u0 & 3) * 8;
  const int r1s = u1 >> 2, k1s = (u1 & 3) * 8;

  const float dt = 1.0f / 16.0f;
  int bidx = 0;

#pragma unroll 1
  for (int stg = 0; stg < 64; ++stg) {
    int s = stg & 3;
    float t0 = dt * (float)(stg >> 2);
    float tval = t0 + ((s == 0) ? 0.0f : (s == 3) ? dt : 0.5f * dt);

    // ===== phase 1: H[ms1 rows, cg1 cols] = tanh(arg @ W1slice + b1 + t) ==
    {
      const unsigned short* gA = arg + (size_t)(ms1 * 128) * DDIM;
      f32x4 acc[4][2] = {};
      async_copy16(gA + r0s * DDIM + k0s, &sA[u0]);
      async_copy16(gA + r1s * DDIM + k1s, &sA[u1]);
#pragma unroll 1
      for (int kt = 0; kt < 16; ++kt) {
        int cur = kt & 1;
        __syncthreads();
        if (kt < 15) {
          int nxt = cur ^ 1;
          int off = (kt + 1) * 32;
          async_copy16(gA + r0s * DDIM + off + k0s, &sA[nxt * 512 + u0]);
          async_copy16(gA + r1s * DDIM + off + k1s, &sA[nxt * 512 + u1]);
        }
        bf16x8 af[4], bfr[2];
#pragma unroll
        for (int i = 0; i < 4; ++i)
          af[i] = sA[cur * 512 + (wm + i * 16 + l15) * 4 + l4];
#pragma unroll
        for (int j = 0; j < 2; ++j) {
          int c = wn + j * 16 + l15;
          bfr[j] = sW1[c * 64 + ((kt * 4 + l4) ^ (c & 7))];
        }
#pragma unroll
        for (int i = 0; i < 4; ++i)
#pragma unroll
          for (int j = 0; j < 2; ++j)
            acc[i][j] = __builtin_amdgcn_mfma_f32_16x16x32_bf16(
                af[i], bfr[j], acc[i][j], 0, 0, 0);
      }
      int colbase = cg1 * 64 + wn + l15;
      int rowbase = ms1 * 128 + wm + l4 * 4;
#pragma unroll
      for (int j = 0; j < 2; ++j) {
        float bias = b1[colbase + j * 16] + tval;
#pragma unroll
        for (int i = 0; i < 4; ++i)
#pragma unroll
          for (int r = 0; r < 4; ++r)
            Hbuf[(size_t)(rowbase + i * 16 + r) * HDIM + colbase + j * 16] =
                f32_to_bf16(tanh_fast(acc[i][j][r] + bias));
      }
    }
    grid_barrier(bar, bidx++);

    // ===== phase 2: part[kc2][ms2 rows, cg2 cols] = H-chunk @ W2slice =====
    {
      const unsigned short* gA = Hbuf + (size_t)(ms2 * 128) * HDIM + kc2 * 512;
      f32x4 acc[4][2] = {};
      async_copy16(gA + r0s * HDIM + k0s, &sA[u0]);
      async_copy16(gA + r1s * HDIM + k1s, &sA[u1]);
#pragma unroll 1
      for (int kt = 0; kt < 16; ++kt) {
        int cur = kt & 1;
        __syncthreads();
        if (kt < 15) {
          int nxt = cur ^ 1;
          int off = (kt + 1) * 32;
          async_copy16(gA + r0s * HDIM + off + k0s, &sA[nxt * 512 + u0]);
          async_copy16(gA + r1s * HDIM + off + k1s, &sA[nxt * 512 + u1]);
        }
        bf16x8 af[4], bfr[2];
#pragma unroll
        for (int i = 0; i < 4; ++i)
          af[i] = sA[cur * 512 + (wm + i * 16 + l15) * 4 + l4];
#pragma unroll
        for (int j = 0; j < 2; ++j) {
          int c = wn + j * 16 + l15;
          bfr[j] = sW2[c * 64 + ((kt * 4 + l4) ^ (c & 7))];
        }
#pragma unroll
        for (int i = 0; i < 4; ++i)
#pragma unroll
          for (int j = 0; j < 2; ++j)
            acc[i][j] = __builtin_amdgcn_mfma_f32_16x16x32_bf16(
                af[i], bfr[j], acc[i][j], 0, 0, 0);
      }
      float* P = part + (size_t)kc2 * (MDIM * DDIM);
      int colbase = cg2 * 64 + wn + l15;
      int rowbase = ms2 * 128 + wm + l4 * 4;
#pragma unroll
      for (int i = 0; i < 4; ++i)
#pragma unroll
        for (int r = 0; r < 4; ++r) {
          float* Prow = P + (size_t)(rowbase + i * 16 + r) * DDIM + colbase;
#pragma unroll
          for (int j = 0; j < 2; ++j)
            Prow[j * 16] = acc[i][j][r];
        }
    }
    grid_barrier(bar, bidx++);

    // ===== phase 3: combine split-K + RK4 epilogue ========================
    {
      float half_dt = 0.5f * dt, dt6 = dt * (1.0f / 6.0f);
#pragma unroll
      for (int i = 0; i < 2; ++i) {
        int f = b * 512 + i * 256 + tid;
        int e = f * 4;
        int col = e & (DDIM - 1);
        float4 p0 = ((const float4*)part)[f];
        float4 p1 = ((const float4*)(part + MDIM * DDIM))[f];
        float4 p2 = ((const float4*)(part + 2 * MDIM * DDIM))[f];
        float4 p3 = ((const float4*)(part + 3 * MDIM * DDIM))[f];
        float4 bb = *(const float4*)(b2 + col);
        float4 k;
        k.x = p0.x + p1.x + p2.x + p3.x + bb.x;
        k.y = p0.y + p1.y + p2.y + p3.y + bb.y;
        k.z = p0.z + p1.z + p2.z + p3.z + bb.z;
        k.w = p0.w + p1.w + p2.w + p3.w + bb.w;
        float4 yv = *(const float4*)(y + e);
        float4 argv;
        if (s == 0) {
          *(float4*)(kacc + e) = k;
          argv.x = yv.x + half_dt * k.x; argv.y = yv.y + half_dt * k.y;
          argv.z = yv.z + half_dt * k.z; argv.w = yv.w + half_dt * k.w;
        } else if (s == 1) {
          float4 ka = *(const float4*)(kacc + e);
          ka.x += 2.0f * k.x; ka.y += 2.0f * k.y; ka.z += 2.0f * k.z; ka.w += 2.0f * k.w;
          *(float4*)(kacc + e) = ka;
          argv.x = yv.x + half_dt * k.x; argv.y = yv.y + half_dt * k.y;
          argv.z = yv.z + half_dt * k.z; argv.w = yv.w + half_dt * k.w;
        } else if (s == 2) {
          float4 ka = *(const float4*)(kacc + e);
          ka.x += 2.0f * k.x; ka.y += 2.0f * k.y; ka.z += 2.0f * k.z; ka.w += 2.0f * k.w;
          *(float4*)(kacc + e) = ka;
          argv.x = yv.x + dt * k.x; argv.y = yv.y + dt * k.y;
          argv.z = yv.z + dt * k.z; argv.w = yv.w + dt * k.w;
        } else {
          float4 ka = *(const float4*)(kacc + e);
          argv.x = yv.x + dt6 * (ka.x + k.x); argv.y = yv.y + dt6 * (ka.y + k.y);
          argv.z = yv.z + dt6 * (ka.z + k.z); argv.w = yv.w + dt6 * (ka.w + k.w);
          *(float4*)(y + e) = argv;
        }
        ushort4 av;
        av.x = f32_to_bf16(argv.x); av.y = f32_to_bf16(argv.y);
        av.z = f32_to_bf16(argv.z); av.w = f32_to_bf16(argv.w);
        *(ushort4*)(arg + e) = av;
      }
    }
    grid_barrier(bar, bidx++);
  }
}

extern "C" void kernel_launch(void* const* d_in, const int* in_sizes, int n_in,
                              void* d_out, int out_size, void* d_ws, size_t ws_size,
                              hipStream_t stream) {
  (void)in_sizes; (void)n_in; (void)out_size; (void)ws_size;
  const float* x  = (const float*)d_in[0];
  const float* W1 = (const float*)d_in[1];
  const float* b1 = (const float*)d_in[2];
  const float* W2 = (const float*)d_in[3];
  const float* b2 = (const float*)d_in[4];
  float* y = (float*)d_out;

  char* ws = (char*)d_ws;
  unsigned short* W1T  = (unsigned short*)(ws);                 // 2MB
  unsigned short* W2T  = (unsigned short*)(ws + (2u << 20));    // 2MB
  unsigned short* Hbuf = (unsigned short*)(ws + (4u << 20));    // 4MB
  unsigned short* arg  = (unsigned short*)(ws + (8u << 20));    // 1MB
  float*          kacc = (float*)(ws + (9u << 20));             // 2MB
  float*          part = (float*)(ws + (11u << 20));            // 8MB
  unsigned*       bar  = (unsigned*)(ws + (19u << 20));         // 1KB
  // total ~19MB + 1KB

  hipFuncSetAttribute((const void*)ode_mega,
                      hipFuncAttributeMaxDynamicSharedMemorySize, DYN_LDS);

  transpose_bf16_kernel<<<256, 256, 0, stream>>>(W1, W1T, DDIM, HDIM);
  transpose_bf16_kernel<<<256, 256, 0, stream>>>(W2, W2T, HDIM, DDIM);
  init_kernel<<<MDIM * DDIM / 256, 256, 0, stream>>>(x, y, arg, bar);

  ode_mega<<<NBLK, 256, DYN_LDS, stream>>>(W1T, W2T, b1, b2, y, kacc, arg,
                                           Hbuf, part, bar);
}

// Round 4
// 1867.396 us; speedup vs baseline: 2.4734x; 2.4734x over previous
//
#include <hip/hip_runtime.h>
#include <cstdint>

// ODEBlock: 16 RK4 steps of f(t,y) = tanh(y@W1 + b1 + t) @ W2 + b2
// B=1024 (M), D=512, H=2048. bf16 MFMA GEMMs, fp32 state/epilogues.
// R4: back to multi-kernel pipeline (R2 structure). Changes vs R1:
//  - gemm2: no split-K, BM=32 BN=32 grid 512, RK4 epilogue fused (combine
//    kernel and part[] traffic eliminated; 2 launches/stage instead of 3)
//  - XOR bank-swizzle on LDS staging in both gemms (global-side permutation,
//    since global_load_lds forces lane-order LDS placement). Kills the
//    16-way ds_read_b128 conflicts (R3 counters: SQ_LDS_BANK_CONFLICT 5e7).

typedef __bf16 bf16x8 __attribute__((ext_vector_type(8)));
typedef float f32x4 __attribute__((ext_vector_type(4)));

#define AS1 __attribute__((address_space(1)))
#define AS3 __attribute__((address_space(3)))

#define MDIM 1024
#define DDIM 512
#define HDIM 2048

__device__ __forceinline__ void async_copy16(const void* g, void* lds) {
  __builtin_amdgcn_global_load_lds((const AS1 void*)g, (AS3 void*)lds, 16, 0, 0);
}

__device__ __forceinline__ unsigned short f32_to_bf16(float f) {
  union { float f; unsigned u; } c; c.f = f;
  unsigned u = c.u + 0x7FFFu + ((c.u >> 16) & 1u);   // RNE
  return (unsigned short)(u >> 16);
}

__device__ __forceinline__ float tanh_fast(float x) {
  float a = __builtin_fabsf(x);
  float e = __expf(-2.0f * a);                        // in (0,1], no overflow
  float r = (1.0f - e) * __builtin_amdgcn_rcpf(1.0f + e);
  return __builtin_copysignf(r, x);
}

// ---- transpose + f32->bf16: out[c*R + r] = bf16(in[r*C + c]) --------------
__global__ __launch_bounds__(256) void transpose_bf16_kernel(
    const float* __restrict__ in, unsigned short* __restrict__ out, int R, int C) {
  __shared__ float tile[64][65];
  int nbc = C >> 6;
  int br = blockIdx.x / nbc, bc = blockIdx.x % nbc;
  int r0 = br * 64, c0 = bc * 64;
  int tr = threadIdx.x >> 6, tc = threadIdx.x & 63;
  for (int i = 0; i < 16; ++i) {
    int row = i * 4 + tr;
    tile[row][tc] = in[(r0 + row) * C + c0 + tc];
  }
  __syncthreads();
  for (int i = 0; i < 16; ++i) {
    int row = i * 4 + tr;
    out[(c0 + row) * R + r0 + tc] = f32_to_bf16(tile[tc][row]);
  }
}

// ---- init: y = x (fp32, lives in d_out), arg = bf16(x) --------------------
__global__ __launch_bounds__(256) void init_kernel(
    const float* __restrict__ x, float* __restrict__ y,
    unsigned short* __restrict__ arg) {
  int i = blockIdx.x * 256 + threadIdx.x;
  float v = x[i];
  y[i] = v;
  arg[i] = f32_to_bf16(v);
}

// ---- GEMM1: H = tanh(arg[1024,512] @ W1 + b1 + t) -------------------------
// W1T [2048,512] bf16 (K-contig). Tile 64x64, BK=64, grid 16x32=512 blocks,
// 4 waves (2x2), wave 32x32. LDS double-buffer; XOR-swizzled staging:
// LDS unit u holds row=u>>3, kgrp=(u&7)^(row&7)  (permute source, not dest).
__global__ __launch_bounds__(256, 2) void gemm1_kernel(
    const unsigned short* __restrict__ A,    // arg bf16 [1024,512]
    const unsigned short* __restrict__ Bt,   // W1T bf16 [2048,512]
    const float* __restrict__ b1, float tval,
    unsigned short* __restrict__ H)          // [1024,2048] bf16
{
  __shared__ bf16x8 sA[2][512];   // 2 x 8KB
  __shared__ bf16x8 sB[2][512];   // 2 x 8KB
  const int K = DDIM;
  const int NITER = DDIM / 64;    // 8
  int bid = blockIdx.x;
  int bm = bid >> 5;              // 0..15
  int bn = bid & 31;              // 0..31
  int tid = threadIdx.x;
  int lane = tid & 63;
  int wid = tid >> 6;
  int l15 = lane & 15;
  int l4 = lane >> 4;
  int wm = (wid >> 1) * 32;
  int wn = (wid & 1) * 32;
  // staging: chunk0 unit=tid (rows 0..31), chunk1 unit=256+tid (rows 32..63)
  int srow = tid >> 3;                              // 0..31
  int skcol = ((tid & 7) ^ (srow & 7)) * 8;         // swizzled k-offset (elems)
  const unsigned short* gA = A + (size_t)(bm * 64 + srow) * K + skcol;
  const unsigned short* gB = Bt + (size_t)(bn * 64 + srow) * K + skcol;
  int sw = l15 & 7;                                 // read-side swizzle
  f32x4 acc[2][2] = {};

  async_copy16(gA, &sA[0][tid]);
  async_copy16(gA + 32 * K, &sA[0][256 + tid]);
  async_copy16(gB, &sB[0][tid]);
  async_copy16(gB + 32 * K, &sB[0][256 + tid]);

#pragma unroll 1
  for (int kt = 0; kt < NITER; ++kt) {
    int cur = kt & 1;
    __syncthreads();
    if (kt + 1 < NITER) {
      int nxt = cur ^ 1;
      int off = (kt + 1) * 64;
      async_copy16(gA + off, &sA[nxt][tid]);
      async_copy16(gA + 32 * K + off, &sA[nxt][256 + tid]);
      async_copy16(gB + off, &sB[nxt][tid]);
      async_copy16(gB + 32 * K + off, &sB[nxt][256 + tid]);
    }
#pragma unroll
    for (int ks = 0; ks < 2; ++ks) {
      int kg = (ks * 4 + l4) ^ sw;
      bf16x8 af[2], bfr[2];
#pragma unroll
      for (int i = 0; i < 2; ++i)
        af[i] = sA[cur][(wm + i * 16 + l15) * 8 + kg];
#pragma unroll
      for (int j = 0; j < 2; ++j)
        bfr[j] = sB[cur][(wn + j * 16 + l15) * 8 + kg];
#pragma unroll
      for (int i = 0; i < 2; ++i)
#pragma unroll
        for (int j = 0; j < 2; ++j)
          acc[i][j] = __builtin_amdgcn_mfma_f32_16x16x32_bf16(
              af[i], bfr[j], acc[i][j], 0, 0, 0);
    }
  }
  // D(m,n): m = l4*4 + reg, n = l15
  int row0 = bm * 64 + wm + l4 * 4;
  int col0 = bn * 64 + wn + l15;
  float bias[2];
  for (int j = 0; j < 2; ++j) bias[j] = b1[col0 + j * 16] + tval;
#pragma unroll
  for (int i = 0; i < 2; ++i)
#pragma unroll
    for (int r = 0; r < 4; ++r) {
      unsigned short* Hrow = H + (size_t)(row0 + i * 16 + r) * HDIM + col0;
#pragma unroll
      for (int j = 0; j < 2; ++j)
        Hrow[j * 16] = f32_to_bf16(tanh_fast(acc[i][j][r] + bias[j]));
    }
}

// ---- GEMM2 fused: k = H[1024,2048] @ W2 + b2, RK4 epilogue ----------------
// W2T [512,2048] bf16. Tile 32x32, BK=64, grid 32x16=512 blocks, 4 waves
// (2x2), wave 16x16, full K (no split). Swizzled staging as gemm1.
// mode 0: kacc = k;            arg = bf16(y + dt/2*k)
// mode 1: kacc += 2k;          arg = bf16(y + dt/2*k)
// mode 2: kacc += 2k;          arg = bf16(y + dt*k)
// mode 3: y += dt/6*(kacc+k);  arg = bf16(y_new)
__global__ __launch_bounds__(256, 2) void gemm2_kernel(
    const unsigned short* __restrict__ A,    // H bf16 [1024,2048]
    const unsigned short* __restrict__ Bt,   // W2T bf16 [512,2048]
    const float* __restrict__ b2,
    float* __restrict__ y, float* __restrict__ kacc,
    unsigned short* __restrict__ arg,
    int mode, float dt)
{
  __shared__ bf16x8 sA[2][256];   // 2 x 4KB
  __shared__ bf16x8 sB[2][256];   // 2 x 4KB
  const int K = HDIM;
  const int NITER = HDIM / 64;    // 32
  int bid = blockIdx.x;
  int bm = bid >> 4;              // 0..31
  int bn = bid & 15;              // 0..15
  int tid = threadIdx.x;
  int lane = tid & 63;
  int wid = tid >> 6;
  int l15 = lane & 15;
  int l4 = lane >> 4;
  int wwm = (wid >> 1) * 16;
  int wwn = (wid & 1) * 16;
  int srow = tid >> 3;                              // 0..31
  int skcol = ((tid & 7) ^ (srow & 7)) * 8;
  const unsigned short* gA = A + (size_t)(bm * 32 + srow) * K + skcol;
  const unsigned short* gB = Bt + (size_t)(bn * 32 + srow) * K + skcol;
  int sw = l15 & 7;
  f32x4 acc = {};

  async_copy16(gA, &sA[0][tid]);
  async_copy16(gB, &sB[0][tid]);

#pragma unroll 1
  for (int kt = 0; kt < NITER; ++kt) {
    int cur = kt & 1;
    __syncthreads();
    if (kt + 1 < NITER) {
      int nxt = cur ^ 1;
      int off = (kt + 1) * 64;
      async_copy16(gA + off, &sA[nxt][tid]);
      async_copy16(gB + off, &sB[nxt][tid]);
    }
#pragma unroll
    for (int ks = 0; ks < 2; ++ks) {
      int kg = (ks * 4 + l4) ^ sw;
      bf16x8 af = sA[cur][(wwm + l15) * 8 + kg];
      bf16x8 bfr = sB[cur][(wwn + l15) * 8 + kg];
      acc = __builtin_amdgcn_mfma_f32_16x16x32_bf16(af, bfr, acc, 0, 0, 0);
    }
  }
  int row0 = bm * 32 + wwm + l4 * 4;
  int col = bn * 32 + wwn + l15;
  float bias = b2[col];
  float half_dt = 0.5f * dt;
  float dt6 = dt * (1.0f / 6.0f);
#pragma unroll
  for (int r = 0; r < 4; ++r) {
    int idx = (row0 + r) * DDIM + col;
    float k = acc[r] + bias;
    float argv;
    if (mode == 0) {
      kacc[idx] = k;
      argv = y[idx] + half_dt * k;
    } else if (mode == 1) {
      kacc[idx] += 2.0f * k;
      argv = y[idx] + half_dt * k;
    } else if (mode == 2) {
      kacc[idx] += 2.0f * k;
      argv = y[idx] + dt * k;
    } else {
      float yn = y[idx] + dt6 * (kacc[idx] + k);
      y[idx] = yn;
      argv = yn;
    }
    arg[idx] = f32_to_bf16(argv);
  }
}

extern "C" void kernel_launch(void* const* d_in, const int* in_sizes, int n_in,
                              void* d_out, int out_size, void* d_ws, size_t ws_size,
                              hipStream_t stream) {
  (void)in_sizes; (void)n_in; (void)out_size; (void)ws_size;
  const float* x  = (const float*)d_in[0];   // [1024,512]
  const float* W1 = (const float*)d_in[1];   // [512,2048]
  const float* b1 = (const float*)d_in[2];   // [2048]
  const float* W2 = (const float*)d_in[3];   // [2048,512]
  const float* b2 = (const float*)d_in[4];   // [512]
  float* y = (float*)d_out;                  // fp32 state lives in d_out

  char* ws = (char*)d_ws;
  unsigned short* W1T  = (unsigned short*)(ws);                    // 2MB  [2048,512] bf16
  unsigned short* W2T  = (unsigned short*)(ws + (2u << 20));       // 2MB  [512,2048] bf16
  unsigned short* Hbuf = (unsigned short*)(ws + (4u << 20));       // 4MB  [1024,2048] bf16
  unsigned short* arg  = (unsigned short*)(ws + (8u << 20));       // 1MB  [1024,512] bf16
  float*          kacc = (float*)(ws + (9u << 20));                // 2MB  [1024,512] f32
  // total 11MB

  transpose_bf16_kernel<<<256, 256, 0, stream>>>(W1, W1T, DDIM, HDIM);
  transpose_bf16_kernel<<<256, 256, 0, stream>>>(W2, W2T, HDIM, DDIM);
  init_kernel<<<MDIM * DDIM / 256, 256, 0, stream>>>(x, y, arg);

  const float dt = 1.0f / 16.0f;
  for (int n = 0; n < 16; ++n) {
    float t0 = dt * (float)n;
    const float ts[4] = {t0, t0 + 0.5f * dt, t0 + 0.5f * dt, t0 + dt};
    for (int s = 0; s < 4; ++s) {
      gemm1_kernel<<<512, 256, 0, stream>>>(arg, W1T, b1, ts[s], Hbuf);
      gemm2_kernel<<<512, 256, 0, stream>>>(Hbuf, W2T, b2, y, kacc, arg, s, dt);
    }
  }
}

// Round 5
// 1638.826 us; speedup vs baseline: 2.8184x; 1.1395x over previous
//
#include <hip/hip_runtime.h>
#include <cstdint>

// ODEBlock: 16 RK4 steps of f(t,y) = tanh(y@W1 + b1 + t) @ W2 + b2
// B=1024 (M), D=512, H=2048. bf16 MFMA GEMMs, fp32 state/epilogues.
// R5: big-BK kernels to amortize the vmcnt(0)-before-barrier drain:
//  - gemm1: 64x128 tile, BK=128 (4 iters), grid 256, wave 32x64, 96KB LDS
//  - gemm2: 64x64 tile, BK=256 (8 iters), grid 128, wave 32x32, 128KB LDS,
//    full-K with fused RK4 epilogue (no split-K, no combine kernel)
//  - XOR bank-swizzle staging everywhere (R3 counter: 5e7 conflicts unswizzled)

typedef __bf16 bf16x8 __attribute__((ext_vector_type(8)));
typedef float f32x4 __attribute__((ext_vector_type(4)));

#define AS1 __attribute__((address_space(1)))
#define AS3 __attribute__((address_space(3)))

#define MDIM 1024
#define DDIM 512
#define HDIM 2048

#define G1_LDS (96*1024)    // sA 2x16KB + sB 2x32KB
#define G2_LDS (128*1024)   // sA 2x32KB + sB 2x32KB

__device__ __forceinline__ void async_copy16(const void* g, void* lds) {
  __builtin_amdgcn_global_load_lds((const AS1 void*)g, (AS3 void*)lds, 16, 0, 0);
}

__device__ __forceinline__ unsigned short f32_to_bf16(float f) {
  union { float f; unsigned u; } c; c.f = f;
  unsigned u = c.u + 0x7FFFu + ((c.u >> 16) & 1u);   // RNE
  return (unsigned short)(u >> 16);
}

__device__ __forceinline__ float tanh_fast(float x) {
  float a = __builtin_fabsf(x);
  float e = __expf(-2.0f * a);
  float r = (1.0f - e) * __builtin_amdgcn_rcpf(1.0f + e);
  return __builtin_copysignf(r, x);
}

// ---- transpose + f32->bf16: out[c*R + r] = bf16(in[r*C + c]) --------------
__global__ __launch_bounds__(256) void transpose_bf16_kernel(
    const float* __restrict__ in, unsigned short* __restrict__ out, int R, int C) {
  __shared__ float tile[64][65];
  int nbc = C >> 6;
  int br = blockIdx.x / nbc, bc = blockIdx.x % nbc;
  int r0 = br * 64, c0 = bc * 64;
  int tr = threadIdx.x >> 6, tc = threadIdx.x & 63;
  for (int i = 0; i < 16; ++i) {
    int row = i * 4 + tr;
    tile[row][tc] = in[(r0 + row) * C + c0 + tc];
  }
  __syncthreads();
  for (int i = 0; i < 16; ++i) {
    int row = i * 4 + tr;
    out[(c0 + row) * R + r0 + tc] = f32_to_bf16(tile[tc][row]);
  }
}

// ---- init: y = x (fp32, lives in d_out), arg = bf16(x) --------------------
__global__ __launch_bounds__(256) void init_kernel(
    const float* __restrict__ x, float* __restrict__ y,
    unsigned short* __restrict__ arg) {
  int i = blockIdx.x * 256 + threadIdx.x;
  float v = x[i];
  y[i] = v;
  arg[i] = f32_to_bf16(v);
}

// ---- GEMM1: H = tanh(arg[1024,512] @ W1 + b1 + t) -------------------------
// W1T [2048,512] bf16 (K-contig). Tile 64x128, BK=128, 4 K-iters, grid
// 16x16=256 (1 block/CU). 4 waves 2x2, wave-tile 32x64 (acc 2x4).
// LDS staging layout (per matrix): unit u (16B) = row*16 + s, holding global
// k-group (s ^ (row&7)) — XOR swizzle so fragment reads are 2-way max.
__global__ __launch_bounds__(256, 1) void gemm1_kernel(
    const unsigned short* __restrict__ A,    // arg bf16 [1024,512]
    const unsigned short* __restrict__ Bt,   // W1T bf16 [2048,512]
    const float* __restrict__ b1, float tval,
    unsigned short* __restrict__ H)          // [1024,2048] bf16
{
  extern __shared__ char lds[];
  bf16x8* sA = (bf16x8*)lds;                 // 2 x 1024 units (32KB)
  bf16x8* sB = (bf16x8*)(lds + 32768);       // 2 x 2048 units (64KB)
  const int K = DDIM;
  const int NITER = 4;                       // 512/128
  int bid = blockIdx.x;
  int bm = bid >> 4;               // 0..15
  int bn = bid & 15;               // 0..15
  int tid = threadIdx.x;
  int lane = tid & 63;
  int wid = tid >> 6;
  int l15 = lane & 15;
  int l4 = lane >> 4;
  int wm = (wid >> 1) * 32;
  int wn = (wid & 1) * 64;
  int sw = l15 & 7;

  // staging source pointers (loop-invariant; add kt*128 per iter)
  const unsigned short* srcA[4];
  const unsigned short* srcB[8];
#pragma unroll
  for (int i = 0; i < 4; ++i) {
    int u = tid + i * 256, r = u >> 4, s = u & 15;
    srcA[i] = A + (size_t)(bm * 64 + r) * K + ((s ^ (r & 7)) * 8);
  }
#pragma unroll
  for (int i = 0; i < 8; ++i) {
    int u = tid + i * 256, r = u >> 4, s = u & 15;
    srcB[i] = Bt + (size_t)(bn * 128 + r) * K + ((s ^ (r & 7)) * 8);
  }

  f32x4 acc[2][4] = {};

#pragma unroll
  for (int i = 0; i < 4; ++i) async_copy16(srcA[i], &sA[tid + i * 256]);
#pragma unroll
  for (int i = 0; i < 8; ++i) async_copy16(srcB[i], &sB[tid + i * 256]);

#pragma unroll 1
  for (int kt = 0; kt < NITER; ++kt) {
    int cur = kt & 1;
    __syncthreads();
    if (kt + 1 < NITER) {
      int nxt = cur ^ 1;
      int off = (kt + 1) * 128;
#pragma unroll
      for (int i = 0; i < 4; ++i)
        async_copy16(srcA[i] + off, &sA[nxt * 1024 + tid + i * 256]);
#pragma unroll
      for (int i = 0; i < 8; ++i)
        async_copy16(srcB[i] + off, &sB[nxt * 2048 + tid + i * 256]);
    }
#pragma unroll
    for (int ks = 0; ks < 4; ++ks) {
      int kg = (ks * 4 + l4) ^ sw;
      bf16x8 af[2], bfr[4];
#pragma unroll
      for (int i = 0; i < 2; ++i)
        af[i] = sA[cur * 1024 + (wm + i * 16 + l15) * 16 + kg];
#pragma unroll
      for (int j = 0; j < 4; ++j)
        bfr[j] = sB[cur * 2048 + (wn + j * 16 + l15) * 16 + kg];
#pragma unroll
      for (int i = 0; i < 2; ++i)
#pragma unroll
        for (int j = 0; j < 4; ++j)
          acc[i][j] = __builtin_amdgcn_mfma_f32_16x16x32_bf16(
              af[i], bfr[j], acc[i][j], 0, 0, 0);
    }
  }
  // D(m,n): m = l4*4 + reg, n = l15
  int row0 = bm * 64 + wm + l4 * 4;
  int col0 = bn * 128 + wn + l15;
  float bias[4];
#pragma unroll
  for (int j = 0; j < 4; ++j) bias[j] = b1[col0 + j * 16] + tval;
#pragma unroll
  for (int i = 0; i < 2; ++i)
#pragma unroll
    for (int r = 0; r < 4; ++r) {
      unsigned short* Hrow = H + (size_t)(row0 + i * 16 + r) * HDIM + col0;
#pragma unroll
      for (int j = 0; j < 4; ++j)
        Hrow[j * 16] = f32_to_bf16(tanh_fast(acc[i][j][r] + bias[j]));
    }
}

// ---- GEMM2: k = H[1024,2048] @ W2 + b2, fused RK4 epilogue ----------------
// W2T [512,2048] bf16. Tile 64x64, BK=256, 8 K-iters, grid 16x8=128.
// 4 waves 2x2, wave-tile 32x32 (acc 2x2). 128KB LDS dbuf.
// mode 0: kacc = k;            arg = bf16(y + dt/2*k)
// mode 1: kacc += 2k;          arg = bf16(y + dt/2*k)
// mode 2: kacc += 2k;          arg = bf16(y + dt*k)
// mode 3: y += dt/6*(kacc+k);  arg = bf16(y_new)
__global__ __launch_bounds__(256, 1) void gemm2_kernel(
    const unsigned short* __restrict__ A,    // H bf16 [1024,2048]
    const unsigned short* __restrict__ Bt,   // W2T bf16 [512,2048]
    const float* __restrict__ b2,
    float* __restrict__ y, float* __restrict__ kacc,
    unsigned short* __restrict__ arg,
    int mode, float dt)
{
  extern __shared__ char lds[];
  bf16x8* sA = (bf16x8*)lds;                 // 2 x 2048 units (64KB)
  bf16x8* sB = (bf16x8*)(lds + 65536);       // 2 x 2048 units (64KB)
  const int K = HDIM;
  const int NITER = 8;                       // 2048/256
  int bid = blockIdx.x;
  int bm = bid >> 3;               // 0..15
  int bn = bid & 7;                // 0..7
  int tid = threadIdx.x;
  int lane = tid & 63;
  int wid = tid >> 6;
  int l15 = lane & 15;
  int l4 = lane >> 4;
  int wm = (wid >> 1) * 32;
  int wn = (wid & 1) * 32;
  int sw = l15 & 7;

  // staging: 64 rows x 32 kgroups = 2048 units per matrix, 8 units/thread
  const unsigned short* srcA[8];
  const unsigned short* srcB[8];
#pragma unroll
  for (int i = 0; i < 8; ++i) {
    int u = tid + i * 256, r = u >> 5, s = u & 31;
    int koff = (s ^ (r & 7)) * 8;
    srcA[i] = A + (size_t)(bm * 64 + r) * K + koff;
    srcB[i] = Bt + (size_t)(bn * 64 + r) * K + koff;
  }

  f32x4 acc[2][2] = {};

#pragma unroll
  for (int i = 0; i < 8; ++i) {
    async_copy16(srcA[i], &sA[tid + i * 256]);
    async_copy16(srcB[i], &sB[tid + i * 256]);
  }

#pragma unroll 1
  for (int kt = 0; kt < NITER; ++kt) {
    int cur = kt & 1;
    __syncthreads();
    if (kt + 1 < NITER) {
      int nxt = cur ^ 1;
      int off = (kt + 1) * 256;
#pragma unroll
      for (int i = 0; i < 8; ++i) {
        async_copy16(srcA[i] + off, &sA[nxt * 2048 + tid + i * 256]);
        async_copy16(srcB[i] + off, &sB[nxt * 2048 + tid + i * 256]);
      }
    }
#pragma unroll
    for (int ks = 0; ks < 8; ++ks) {
      int kg = (ks * 4 + l4) ^ sw;
      bf16x8 af[2], bfr[2];
#pragma unroll
      for (int i = 0; i < 2; ++i)
        af[i] = sA[cur * 2048 + (wm + i * 16 + l15) * 32 + kg];
#pragma unroll
      for (int j = 0; j < 2; ++j)
        bfr[j] = sB[cur * 2048 + (wn + j * 16 + l15) * 32 + kg];
#pragma unroll
      for (int i = 0; i < 2; ++i)
#pragma unroll
        for (int j = 0; j < 2; ++j)
          acc[i][j] = __builtin_amdgcn_mfma_f32_16x16x32_bf16(
              af[i], bfr[j], acc[i][j], 0, 0, 0);
    }
  }
  int row0 = bm * 64 + wm + l4 * 4;
  int col0 = bn * 64 + wn + l15;
  float half_dt = 0.5f * dt;
  float dt6 = dt * (1.0f / 6.0f);
  float bias[2];
#pragma unroll
  for (int j = 0; j < 2; ++j) bias[j] = b2[col0 + j * 16];
#pragma unroll
  for (int i = 0; i < 2; ++i)
#pragma unroll
    for (int r = 0; r < 4; ++r) {
      int row = row0 + i * 16 + r;
#pragma unroll
      for (int j = 0; j < 2; ++j) {
        int idx = row * DDIM + col0 + j * 16;
        float k = acc[i][j][r] + bias[j];
        float argv;
        if (mode == 0) {
          kacc[idx] = k;
          argv = y[idx] + half_dt * k;
        } else if (mode == 1) {
          kacc[idx] += 2.0f * k;
          argv = y[idx] + half_dt * k;
        } else if (mode == 2) {
          kacc[idx] += 2.0f * k;
          argv = y[idx] + dt * k;
        } else {
          float yn = y[idx] + dt6 * (kacc[idx] + k);
          y[idx] = yn;
          argv = yn;
        }
        arg[idx] = f32_to_bf16(argv);
      }
    }
}

extern "C" void kernel_launch(void* const* d_in, const int* in_sizes, int n_in,
                              void* d_out, int out_size, void* d_ws, size_t ws_size,
                              hipStream_t stream) {
  (void)in_sizes; (void)n_in; (void)out_size; (void)ws_size;
  const float* x  = (const float*)d_in[0];   // [1024,512]
  const float* W1 = (const float*)d_in[1];   // [512,2048]
  const float* b1 = (const float*)d_in[2];   // [2048]
  const float* W2 = (const float*)d_in[3];   // [2048,512]
  const float* b2 = (const float*)d_in[4];   // [512]
  float* y = (float*)d_out;                  // fp32 state lives in d_out

  char* ws = (char*)d_ws;
  unsigned short* W1T  = (unsigned short*)(ws);                    // 2MB  [2048,512] bf16
  unsigned short* W2T  = (unsigned short*)(ws + (2u << 20));       // 2MB  [512,2048] bf16
  unsigned short* Hbuf = (unsigned short*)(ws + (4u << 20));       // 4MB  [1024,2048] bf16
  unsigned short* arg  = (unsigned short*)(ws + (8u << 20));       // 1MB  [1024,512] bf16
  float*          kacc = (float*)(ws + (9u << 20));                // 2MB  [1024,512] f32
  // total 11MB

  hipFuncSetAttribute((const void*)gemm1_kernel,
                      hipFuncAttributeMaxDynamicSharedMemorySize, G1_LDS);
  hipFuncSetAttribute((const void*)gemm2_kernel,
                      hipFuncAttributeMaxDynamicSharedMemorySize, G2_LDS);

  transpose_bf16_kernel<<<256, 256, 0, stream>>>(W1, W1T, DDIM, HDIM);
  transpose_bf16_kernel<<<256, 256, 0, stream>>>(W2, W2T, HDIM, DDIM);
  init_kernel<<<MDIM * DDIM / 256, 256, 0, stream>>>(x, y, arg);

  const float dt = 1.0f / 16.0f;
  for (int n = 0; n < 16; ++n) {
    float t0 = dt * (float)n;
    const float ts[4] = {t0, t0 + 0.5f * dt, t0 + 0.5f * dt, t0 + dt};
    for (int s = 0; s < 4; ++s) {
      gemm1_kernel<<<256, 256, G1_LDS, stream>>>(arg, W1T, b1, ts[s], Hbuf);
      gemm2_kernel<<<128, 256, G2_LDS, stream>>>(Hbuf, W2T, b2, y, kacc, arg, s, dt);
    }
  }
}